// Round 7
// baseline (368.547 us; speedup 1.0000x reference)
//
#include <hip/hip_runtime.h>
#include <math.h>

// Shift-GCN fused block, N=64,T=256,V=25,C=D=64. bf16-MFMA GEMM, fp32 elsewhere.
// shift_in:  gathered(w,c) = raw((w+c)%25, c)
// shift_out: lin (w,d) -> output node wp=(w+d)%25
// Linear_bias cancels in BatchNorm -> ignored.
//
// ws layout (floats):
//   [0,800)       mask bf16 (1600 ushort) RAW-space: maskm[wr*64+c]=bf16(tanh(FM[(wr-c)%25][c])+1)
//   [4800,6400)   mul[q] = gamma[out(q)] * istd[q]
//   [6400,8000)   add[q] = beta[out(q)] - mean[q]*mul[q]
//   [8000,8000+64*3200)  64 replica partial accumulators (sum[1600], sumsq[1600] each)

typedef __attribute__((ext_vector_type(8))) short bf16x8;
typedef __attribute__((ext_vector_type(4))) float f32x4;

__device__ __forceinline__ ushort f2bf(float f) {
  uint u; __builtin_memcpy(&u, &f, 4);
  u += 0x7fffu + ((u >> 16) & 1u);       // RNE
  return (ushort)(u >> 16);
}
__device__ __forceinline__ float bf2f(ushort b) {
  uint u = ((uint)b) << 16; float f; __builtin_memcpy(&f, &u, 4); return f;
}

__global__ void k_prep(const float* __restrict__ mask, float* __restrict__ ws) {
  int i = blockIdx.x * 256 + threadIdx.x;
  if (i < 1600) {
    int w = i >> 6, c = i & 63;
    int wr = (w + c) % 25;
    ((ushort*)ws)[wr * 64 + c] = f2bf(tanhf(mask[i]) + 1.0f);
  }
  for (int j = 8000 + i; j < 8000 + 64 * 3200; j += gridDim.x * 256)
    ws[j] = 0.0f;
}

__global__ void k_finalize(const float* __restrict__ gamma,
                           const float* __restrict__ beta,
                           float* __restrict__ ws) {
  int q = blockIdx.x * 256 + threadIdx.x;
  if (q >= 1600) return;
  float sum = 0.f, sq = 0.f;
  #pragma unroll 4
  for (int s = 0; s < 64; ++s) {
    sum += ws[8000 + s * 3200 + q];
    sq  += ws[8000 + s * 3200 + 1600 + q];
  }
  const float inv = 1.0f / 16384.0f;
  float mean = sum * inv;
  float var  = sq * inv - mean * mean;
  float istd = rsqrtf(var + 1e-5f);
  int w = q >> 6, d = q & 63;
  int p = ((w + d) % 25) * 64 + d;
  float mul = gamma[p] * istd;
  ws[4800 + q] = mul;
  ws[6400 + q] = beta[p] - mean * mul;
}

template<int PASS>
__launch_bounds__(256, 4)
__global__ void k_main(const float* __restrict__ x0,
                       const float* __restrict__ Wg,
                       float* ws,
                       float* __restrict__ out) {
  __shared__ __align__(8)  ushort s_maskm[1600];
  __shared__ __align__(16) ushort s_A[4096];                // [64 rows][64 c] bf16, XOR-swizzled
  __shared__ float s_raw[PASS == 2 ? 3400 : 4];             // [2][25*68] fp32 raw rows
  __shared__ float s_aux[3200];                             // pass1: stat combine | pass2: y tile

  const int tid = threadIdx.x;
  const int lr  = tid & 63;
  const int wid = tid >> 6;

  for (int i = tid; i < 800; i += 256)
    ((uint*)s_maskm)[i] = ((const uint*)ws)[i];
  for (int i = tid; i < 2048; i += 256)
    ((uint*)s_A)[i] = 0u;

  // W -> register-resident B fragments
  bf16x8 wfrag[2][4];
  #pragma unroll
  for (int ks = 0; ks < 2; ++ks)
    #pragma unroll
    for (int nt = 0; nt < 4; ++nt) {
      const int d = nt * 16 + (lr & 15);
      const int cb = ks * 32 + (lr >> 4) * 8;
      #pragma unroll
      for (int j = 0; j < 8; ++j)
        wfrag[ks][nt][j] = (short)f2bf(Wg[(cb + j) * 64 + d]);
    }

  float cmul[16], cadd[16];
  float ssum[16], ssq[16];
  #pragma unroll
  for (int k = 0; k < 16; ++k) { ssum[k] = 0.f; ssq[k] = 0.f; }
  if constexpr (PASS == 2) {
    #pragma unroll
    for (int nt = 0; nt < 4; ++nt)
      #pragma unroll
      for (int r = 0; r < 4; ++r) {
        int row = wid * 16 + (lr >> 4) * 4 + r;
        int w = row & 31;
        int d = nt * 16 + (lr & 15);
        int qq = (w < 25) ? (w * 64 + d) : 0;
        cmul[nt * 4 + r] = ws[4800 + qq];
        cadd[nt * 4 + r] = ws[6400 + qq];
      }
  }

  const int row_base = blockIdx.x * 16;
  const int n  = row_base >> 8;
  const int t0 = row_base & 255;

  if constexpr (PASS == 1) {
    for (int i = tid; i < 3200; i += 256) s_aux[i] = 0.f;
  }
  __syncthreads();

  // ---- register double-buffer for row-pair staging (T14) ----
  float4 cur0, cur1, cur2, cur3, nxt0, nxt1, nxt2, nxt3;
  {
    const float4* p = (const float4*)(x0 + (size_t)row_base * 1600);
    cur0 = p[tid]; cur1 = p[tid + 256]; cur2 = p[tid + 512];
    if (tid < 32) cur3 = p[tid + 768];
  }

  for (int rp = 0; rp < 16; rp += 2) {
    // ---- scatter/convert current row-pair from registers into LDS ----
    #pragma unroll
    for (int s = 0; s < 4; ++s) {
      if (s == 3 && tid >= 32) break;
      int i4 = (s < 3) ? (tid + s * 256) : (768 + tid);
      float4 v = (s == 0) ? cur0 : (s == 1) ? cur1 : (s == 2) ? cur2 : cur3;
      int r2 = (i4 >= 400) ? 1 : 0;
      int p4 = (i4 - r2 * 400) * 4;
      int wr = p4 >> 6, c0 = p4 & 63;
      if constexpr (PASS == 2)
        *(float4*)&s_raw[r2 * 1700 + wr * 68 + c0] = v;
      uint2 mm = *(const uint2*)&s_maskm[p4];
      float va[4] = {v.x, v.y, v.z, v.w};
      float ma[4] = {bf2f((ushort)(mm.x & 0xffff)), bf2f((ushort)(mm.x >> 16)),
                     bf2f((ushort)(mm.y & 0xffff)), bf2f((ushort)(mm.y >> 16))};
      int wbase = wr + 100 - c0;
      #pragma unroll
      for (int j = 0; j < 4; ++j) {
        int w = (wbase - j) % 25;
        int row = r2 * 32 + w;
        int byte = (row * 128 + (c0 + j) * 2) ^ ((w & 7) << 4);
        *(ushort*)((char*)s_A + byte) = f2bf(va[j] * ma[j]);
      }
    }

    // ---- issue next row-pair's global loads (fly across barriers + MFMA) ----
    if (rp + 2 < 16) {
      const float4* p = (const float4*)(x0 + (size_t)(row_base + rp + 2) * 1600);
      nxt0 = p[tid]; nxt1 = p[tid + 256]; nxt2 = p[tid + 512];
      if (tid < 32) nxt3 = p[tid + 768];
    }
    __syncthreads();

    // ---- MFMA: per wave one 16-row M-tile x N=64, K=64 ----
    const int arow = wid * 16 + (lr & 15);
    bf16x8 afrag[2];
    #pragma unroll
    for (int ks = 0; ks < 2; ++ks) {
      int byte = (arow * 128 + ks * 64 + (lr >> 4) * 16) ^ ((arow & 7) << 4);
      afrag[ks] = *(const bf16x8*)((const char*)s_A + byte);
    }
    f32x4 acc[4];
    #pragma unroll
    for (int nt = 0; nt < 4; ++nt) {
      acc[nt] = (f32x4){0.f, 0.f, 0.f, 0.f};
      #pragma unroll
      for (int ks = 0; ks < 2; ++ks)
        acc[nt] = __builtin_amdgcn_mfma_f32_16x16x32_bf16(afrag[ks], wfrag[ks][nt], acc[nt], 0, 0, 0);
    }

    if constexpr (PASS == 1) {
      #pragma unroll
      for (int nt = 0; nt < 4; ++nt)
        #pragma unroll
        for (int r = 0; r < 4; ++r) {
          float y = acc[nt][r];
          ssum[nt * 4 + r] += y;
          ssq [nt * 4 + r]  = fmaf(y, y, ssq[nt * 4 + r]);
        }
      __syncthreads();
    } else {
      #pragma unroll
      for (int nt = 0; nt < 4; ++nt)
        #pragma unroll
        for (int r = 0; r < 4; ++r) {
          int row = wid * 16 + (lr >> 4) * 4 + r;
          int r2 = row >> 5;
          int w  = row & 31;
          if (w < 25) {
            int d  = nt * 16 + (lr & 15);
            int wp = (w + d) % 25;
            float y = fmaf(acc[nt][r], cmul[nt * 4 + r], cadd[nt * 4 + r]);
            y += s_raw[r2 * 1700 + wp * 68 + d];
            s_aux[d * 50 + r2 * 25 + wp] = fmaxf(y, 0.f);
          }
        }
      __syncthreads();
      const size_t obase = (size_t)n * 409600 + (size_t)(t0 + rp) * 25;
      for (int i = tid; i < 3200; i += 256) {
        int d   = i / 50;
        int rem = i - d * 50;
        int r2  = rem / 25;
        int wp  = rem - r2 * 25;
        out[obase + (size_t)d * 6400 + r2 * 25 + wp] = s_aux[i];
      }
      __syncthreads();
    }

    if (rp + 2 < 16) {
      cur0 = nxt0; cur1 = nxt1; cur2 = nxt2;
      if (tid < 32) cur3 = nxt3;
    }
  }

  if constexpr (PASS == 1) {
    // block-level combine in LDS (each column has exactly 2 contributors)
    #pragma unroll
    for (int nt = 0; nt < 4; ++nt)
      #pragma unroll
      for (int r = 0; r < 4; ++r) {
        int row = wid * 16 + (lr >> 4) * 4 + r;
        int w = row & 31;
        if (w < 25) {
          int q = w * 64 + nt * 16 + (lr & 15);
          atomicAdd(&s_aux[q],        ssum[nt * 4 + r]);
          atomicAdd(&s_aux[1600 + q], ssq [nt * 4 + r]);
        }
      }
    __syncthreads();
    // replica-spread global accumulation: 64 replicas, 16 blocks each
    float* rep = ws + 8000 + (blockIdx.x & 63) * 3200;
    for (int i = tid; i < 3200; i += 256)
      atomicAdd(&rep[i], s_aux[i]);
  }
}

extern "C" void kernel_launch(void* const* d_in, const int* in_sizes, int n_in,
                              void* d_out, int out_size, void* d_ws, size_t ws_size,
                              hipStream_t stream) {
  const float* x0    = (const float*)d_in[0];
  const float* W     = (const float*)d_in[1];
  // d_in[2] Linear_bias: cancels in BN, ignored
  const float* mask  = (const float*)d_in[3];
  const float* gamma = (const float*)d_in[4];
  const float* beta  = (const float*)d_in[5];
  // d_in[6], d_in[7] shift indices: computed analytically, ignored
  float* ws  = (float*)d_ws;
  float* out = (float*)d_out;

  k_prep    <<<200,  256, 0, stream>>>(mask, ws);
  k_main<1> <<<1024, 256, 0, stream>>>(x0, W, ws, out);
  k_finalize<<<7,    256, 0, stream>>>(gamma, beta, ws);
  k_main<2> <<<1024, 256, 0, stream>>>(x0, W, ws, out);
}

// Round 8
// 364.241 us; speedup vs baseline: 1.0118x; 1.0118x over previous
//
#include <hip/hip_runtime.h>
#include <math.h>

// Shift-GCN fused block, N=64,T=256,V=25,C=D=64.
// Main path (3 kernels, needs ~131MB ws):
//   K1 k_gemm  : shift-in+mask+bf16 MFMA, y_raw(f32,[t][w][d]) -> ws, stat partials -> slots
//   K2 k_reduce/k_params : slot tree-reduce -> BN params (out-space)
//   K3 k_epi   : BN + shift-out + residual + ReLU + (n,d,t,u) transpose, line-aligned stores
// Fallback path (ws too small): round-7 two-pass kernels.
//
// shift_in:  gathered(w,c) = raw((w+c)%25, c)
// shift_out: out node u at chan d reads lin (w,d), w=(u-d)%25
// Linear_bias cancels in BatchNorm -> ignored.

typedef __attribute__((ext_vector_type(8))) short bf16x8;
typedef __attribute__((ext_vector_type(4))) float f32x4;

__device__ __forceinline__ ushort f2bf(float f) {
  uint u; __builtin_memcpy(&u, &f, 4);
  u += 0x7fffu + ((u >> 16) & 1u);       // RNE
  return (ushort)(u >> 16);
}
__device__ __forceinline__ float bf2f(ushort b) {
  uint u = ((uint)b) << 16; float f; __builtin_memcpy(&f, &u, 4); return f;
}

// ================= main path =================
// ws float offsets
#define YOFF    0u
#define SLOTOFF 26214400u                  // 2048 slots x 3200
#define SUMOFF  32768000u                  // 3200
#define PRMOFF  32771200u                  // mulU[1600], addU[1600]
#define WS_NEED ((size_t)(32771200u + 3200u) * 4u)

__global__ __launch_bounds__(256, 5)
void k_gemm(const float* __restrict__ x0, const float* __restrict__ Wg,
            const float* __restrict__ FM, float* __restrict__ ws) {
  __shared__ ushort s_maskm[1600];     // raw-space bf16 mask
  __shared__ float  s_u[3200];         // first 8KB doubles as bf16 A tile (XOR-swizzled)
  ushort* s_A = (ushort*)s_u;

  const int tid = threadIdx.x;
  const int lr  = tid & 63;
  const int wid = tid >> 6;

  // mask: tanh computed per-block (cheap), stored raw-space
  for (int i = tid; i < 1600; i += 256) {
    int w = i >> 6, c = i & 63;
    int wr = (w + c) % 25;
    s_maskm[wr * 64 + c] = f2bf(tanhf(FM[i]) + 1.0f);
  }
  for (int i = tid; i < 2048; i += 256) ((uint*)s_A)[i] = 0u;  // incl. pad rows

  // W -> register-resident B fragments (16x16x32: col=nt*16+(lr&15), k=ks*32+(lr>>4)*8+j)
  bf16x8 wfrag[2][4];
  #pragma unroll
  for (int ks = 0; ks < 2; ++ks)
    #pragma unroll
    for (int nt = 0; nt < 4; ++nt) {
      const int d = nt * 16 + (lr & 15);
      const int cb = ks * 32 + (lr >> 4) * 8;
      #pragma unroll
      for (int j = 0; j < 8; ++j)
        wfrag[ks][nt][j] = (short)f2bf(Wg[(cb + j) * 64 + d]);
    }

  float ssum[16], ssq[16];
  #pragma unroll
  for (int k = 0; k < 16; ++k) { ssum[k] = 0.f; ssq[k] = 0.f; }

  const int row_base = blockIdx.x * 8;
  __syncthreads();

  for (int rp = 0; rp < 8; rp += 2) {
    const float* xrow = x0 + (size_t)(row_base + rp) * 1600;
    // stage+gather+mask: scatter bf16 into swizzled A tile (rows 0-24 / 32-56)
    for (int i4 = tid; i4 < 800; i4 += 256) {
      float4 v = ((const float4*)xrow)[i4];
      int r2 = (i4 >= 400) ? 1 : 0;
      int p4 = (i4 - r2 * 400) * 4;
      int wr = p4 >> 6, c0 = p4 & 63;
      uint2 mm = *(const uint2*)&s_maskm[p4];
      float va[4] = {v.x, v.y, v.z, v.w};
      float ma[4] = {bf2f((ushort)(mm.x & 0xffff)), bf2f((ushort)(mm.x >> 16)),
                     bf2f((ushort)(mm.y & 0xffff)), bf2f((ushort)(mm.y >> 16))};
      int w = (wr + 100 - c0) % 25;              // gathered node for j=0
      #pragma unroll
      for (int j = 0; j < 4; ++j) {
        int row = r2 * 32 + w;
        int byte = (row * 128 + (c0 + j) * 2) ^ ((w & 7) << 4);
        *(ushort*)((char*)s_A + byte) = f2bf(va[j] * ma[j]);
        w = (w == 0) ? 24 : (w - 1);             // decrement mod 25
      }
    }
    __syncthreads();

    // MFMA: per wave one 16-row M-tile x N=64, K=64
    const int arow = wid * 16 + (lr & 15);
    bf16x8 afrag[2];
    #pragma unroll
    for (int ks = 0; ks < 2; ++ks) {
      int byte = (arow * 128 + ks * 64 + (lr >> 4) * 16) ^ ((arow & 7) << 4);
      afrag[ks] = *(const bf16x8*)((const char*)s_A + byte);
    }
    f32x4 acc[4];
    #pragma unroll
    for (int nt = 0; nt < 4; ++nt) {
      acc[nt] = (f32x4){0.f, 0.f, 0.f, 0.f};
      #pragma unroll
      for (int ks = 0; ks < 2; ++ks)
        acc[nt] = __builtin_amdgcn_mfma_f32_16x16x32_bf16(afrag[ks], wfrag[ks][nt], acc[nt], 0, 0, 0);
    }

    // stats + full-line y store ([t][w][d] layout: 4x64B lines per wave-instr)
    #pragma unroll
    for (int nt = 0; nt < 4; ++nt)
      #pragma unroll
      for (int r = 0; r < 4; ++r) {
        float y = acc[nt][r];
        ssum[nt * 4 + r] += y;                   // pad rows contribute 0
        ssq [nt * 4 + r]  = fmaf(y, y, ssq[nt * 4 + r]);
        int mrow = wid * 16 + (lr >> 4) * 4 + r;
        int r2 = mrow >> 5, w = mrow & 31;
        if (w < 25)
          ws[YOFF + (size_t)(row_base + rp + r2) * 1600 + w * 64 + nt * 16 + (lr & 15)] = y;
      }
    __syncthreads();
  }

  // combine the 2 per-column contributors (different wave halves), store slot
  #pragma unroll
  for (int nt = 0; nt < 4; ++nt)
    #pragma unroll
    for (int r = 0; r < 4; ++r) {
      int mrow = wid * 16 + (lr >> 4) * 4 + r;
      int w = mrow & 31;
      if (mrow < 32 && w < 25) {
        int q = w * 64 + nt * 16 + (lr & 15);
        s_u[q]        = ssum[nt * 4 + r];
        s_u[1600 + q] = ssq [nt * 4 + r];
      }
    }
  __syncthreads();
  #pragma unroll
  for (int nt = 0; nt < 4; ++nt)
    #pragma unroll
    for (int r = 0; r < 4; ++r) {
      int mrow = wid * 16 + (lr >> 4) * 4 + r;
      int w = mrow & 31;
      if (mrow >= 32 && w < 25) {
        int q = w * 64 + nt * 16 + (lr & 15);
        s_u[q]        += ssum[nt * 4 + r];
        s_u[1600 + q] += ssq [nt * 4 + r];
      }
    }
  __syncthreads();
  for (int i = tid; i < 3200; i += 256)
    ws[SLOTOFF + (size_t)blockIdx.x * 3200 + i] = s_u[i];
}

__global__ void k_reduce(float* __restrict__ ws) {
  int gid = blockIdx.x * 256 + threadIdx.x;     // 100 blocks -> 25600 threads
  int q  = gid % 3200;
  int sc = gid / 3200;                          // 8 slot-chunks of 256
  size_t base = SLOTOFF + (size_t)sc * 256 * 3200 + q;
  float s = 0.f;
  #pragma unroll 8
  for (int k = 0; k < 256; ++k)
    s += ws[base + (size_t)k * 3200];
  atomicAdd(&ws[SUMOFF + q], s);                // 8 contributors per column
}

__global__ void k_params(const float* __restrict__ gamma,
                         const float* __restrict__ beta,
                         float* __restrict__ ws) {
  int p = blockIdx.x * 256 + threadIdx.x;
  if (p >= 1600) return;
  int u = p >> 6, d = p & 63;
  int w = (u + 75 - d) % 25;                    // lin-space node feeding out col (u,d)
  int q = w * 64 + d;
  const float inv = 1.0f / 16384.0f;
  float mean = ws[SUMOFF + q] * inv;
  float var  = ws[SUMOFF + 1600 + q] * inv - mean * mean;
  float istd = rsqrtf(var + 1e-5f);
  float mul = gamma[p] * istd;
  ws[PRMOFF + p]        = mul;
  ws[PRMOFF + 1600 + p] = beta[p] - mean * mul;
}

__global__ __launch_bounds__(256, 2)
void k_epi(const float* __restrict__ x0, const float* __restrict__ ws,
           float* __restrict__ out) {
  __shared__ float yt[16 * 25 * 17];   // [t][w][dd] pad17 (bank-spread)
  __shared__ float xt[16 * 25 * 17];   // [t][u][dd]
  __shared__ float pm[2][25 * 17];     // mulU/addU [u][dd]

  const int tid = threadIdx.x;
  const int n  = blockIdx.x >> 4;
  const int t0 = (blockIdx.x & 15) * 16;
  const size_t base_in = ((size_t)n * 256 + t0) * 1600;
  const size_t base_out = (size_t)n * 409600 + (size_t)t0 * 25;

  for (int dq = 0; dq < 4; ++dq) {
    const int dbase = dq * 16;
    // stage y and x0 tiles (float4; 64B runs)
    for (int i4 = tid; i4 < 1600; i4 += 256) {
      int t = i4 / 100, rem = i4 % 100;
      int w = rem >> 2, f4 = rem & 3;
      size_t g = base_in + (size_t)t * 1600 + w * 64 + dbase + f4 * 4;
      float4 vy = *(const float4*)&ws[YOFF + g];
      float4 vx = *(const float4*)&x0[g];
      *(float4*)&yt[(t * 25 + w) * 17 + f4 * 4] = vy;
      *(float4*)&xt[(t * 25 + w) * 17 + f4 * 4] = vx;
    }
    for (int i = tid; i < 400; i += 256) {
      int u = i >> 4, dd = i & 15;
      pm[0][u * 17 + dd] = ws[PRMOFF + u * 64 + dbase + dd];
      pm[1][u * 17 + dd] = ws[PRMOFF + 1600 + u * 64 + dbase + dd];
    }
    __syncthreads();

    // out: 16 d x 400 (t,u) positions, 1600B line-aligned runs per d
    for (int i4 = tid; i4 < 1600; i4 += 256) {
      int dl = i4 / 100;
      int d  = dbase + dl;
      int p4 = (i4 % 100) * 4;
      float4 o;
      #pragma unroll
      for (int e = 0; e < 4; ++e) {
        int p = p4 + e;
        int t = p / 25, u = p - t * 25;
        int w = (u + 75 - d) % 25;
        float val = fmaf(yt[(t * 25 + w) * 17 + dl], pm[0][u * 17 + dl],
                         pm[1][u * 17 + dl]) + xt[(t * 25 + u) * 17 + dl];
        o[e] = fmaxf(val, 0.f);
      }
      *(float4*)&out[base_out + (size_t)d * 6400 + p4] = o;
    }
    __syncthreads();
  }
}

// ================= fallback path (round-7, proven) =================
__global__ void k_prep_f(const float* __restrict__ mask, float* __restrict__ ws) {
  int i = blockIdx.x * 256 + threadIdx.x;
  if (i < 1600) {
    int w = i >> 6, c = i & 63;
    int wr = (w + c) % 25;
    ((ushort*)ws)[wr * 64 + c] = f2bf(tanhf(mask[i]) + 1.0f);
  }
  for (int j = 8000 + i; j < 8000 + 64 * 3200; j += gridDim.x * 256)
    ws[j] = 0.0f;
}

__global__ void k_finalize_f(const float* __restrict__ gamma,
                             const float* __restrict__ beta,
                             float* __restrict__ ws) {
  int q = blockIdx.x * 256 + threadIdx.x;
  if (q >= 1600) return;
  float sum = 0.f, sq = 0.f;
  #pragma unroll 4
  for (int s = 0; s < 64; ++s) {
    sum += ws[8000 + s * 3200 + q];
    sq  += ws[8000 + s * 3200 + 1600 + q];
  }
  const float inv = 1.0f / 16384.0f;
  float mean = sum * inv;
  float var  = sq * inv - mean * mean;
  float istd = rsqrtf(var + 1e-5f);
  int w = q >> 6, d = q & 63;
  int p = ((w + d) % 25) * 64 + d;
  float mul = gamma[p] * istd;
  ws[4800 + q] = mul;
  ws[6400 + q] = beta[p] - mean * mul;
}

template<int PASS>
__launch_bounds__(256, 4)
__global__ void k_main_f(const float* __restrict__ x0,
                         const float* __restrict__ Wg,
                         float* ws,
                         float* __restrict__ out) {
  __shared__ __align__(8)  ushort s_maskm[1600];
  __shared__ __align__(16) ushort s_A[4096];
  __shared__ float s_raw[PASS == 2 ? 3400 : 4];
  __shared__ float s_aux[3200];

  const int tid = threadIdx.x;
  const int lr  = tid & 63;
  const int wid = tid >> 6;

  for (int i = tid; i < 800; i += 256)
    ((uint*)s_maskm)[i] = ((const uint*)ws)[i];
  for (int i = tid; i < 2048; i += 256)
    ((uint*)s_A)[i] = 0u;

  bf16x8 wfrag[2][4];
  #pragma unroll
  for (int ks = 0; ks < 2; ++ks)
    #pragma unroll
    for (int nt = 0; nt < 4; ++nt) {
      const int d = nt * 16 + (lr & 15);
      const int cb = ks * 32 + (lr >> 4) * 8;
      #pragma unroll
      for (int j = 0; j < 8; ++j)
        wfrag[ks][nt][j] = (short)f2bf(Wg[(cb + j) * 64 + d]);
    }

  float cmul[16], cadd[16];
  float ssum[16], ssq[16];
  #pragma unroll
  for (int k = 0; k < 16; ++k) { ssum[k] = 0.f; ssq[k] = 0.f; }
  if constexpr (PASS == 2) {
    #pragma unroll
    for (int nt = 0; nt < 4; ++nt)
      #pragma unroll
      for (int r = 0; r < 4; ++r) {
        int row = wid * 16 + (lr >> 4) * 4 + r;
        int w = row & 31;
        int d = nt * 16 + (lr & 15);
        int qq = (w < 25) ? (w * 64 + d) : 0;
        cmul[nt * 4 + r] = ws[4800 + qq];
        cadd[nt * 4 + r] = ws[6400 + qq];
      }
  }

  const int row_base = blockIdx.x * 16;
  const int n  = row_base >> 8;
  const int t0 = row_base & 255;

  if constexpr (PASS == 1) {
    for (int i = tid; i < 3200; i += 256) s_aux[i] = 0.f;
  }
  __syncthreads();

  for (int rp = 0; rp < 16; rp += 2) {
    const float* xrow = x0 + (size_t)(row_base + rp) * 1600;
    for (int i4 = tid; i4 < 800; i4 += 256) {
      float4 v = ((const float4*)xrow)[i4];
      int r2 = (i4 >= 400) ? 1 : 0;
      int p4 = (i4 - r2 * 400) * 4;
      int wr = p4 >> 6, c0 = p4 & 63;
      if constexpr (PASS == 2)
        *(float4*)&s_raw[r2 * 1700 + wr * 68 + c0] = v;
      uint2 mm = *(const uint2*)&s_maskm[p4];
      float va[4] = {v.x, v.y, v.z, v.w};
      float ma[4] = {bf2f((ushort)(mm.x & 0xffff)), bf2f((ushort)(mm.x >> 16)),
                     bf2f((ushort)(mm.y & 0xffff)), bf2f((ushort)(mm.y >> 16))};
      int wbase = wr + 100 - c0;
      #pragma unroll
      for (int j = 0; j < 4; ++j) {
        int w = (wbase - j) % 25;
        int row = r2 * 32 + w;
        int byte = (row * 128 + (c0 + j) * 2) ^ ((w & 7) << 4);
        *(ushort*)((char*)s_A + byte) = f2bf(va[j] * ma[j]);
      }
    }
    __syncthreads();

    const int arow = wid * 16 + (lr & 15);
    bf16x8 afrag[2];
    #pragma unroll
    for (int ks = 0; ks < 2; ++ks) {
      int byte = (arow * 128 + ks * 64 + (lr >> 4) * 16) ^ ((arow & 7) << 4);
      afrag[ks] = *(const bf16x8*)((const char*)s_A + byte);
    }
    f32x4 acc[4];
    #pragma unroll
    for (int nt = 0; nt < 4; ++nt) {
      acc[nt] = (f32x4){0.f, 0.f, 0.f, 0.f};
      #pragma unroll
      for (int ks = 0; ks < 2; ++ks)
        acc[nt] = __builtin_amdgcn_mfma_f32_16x16x32_bf16(afrag[ks], wfrag[ks][nt], acc[nt], 0, 0, 0);
    }

    if constexpr (PASS == 1) {
      #pragma unroll
      for (int nt = 0; nt < 4; ++nt)
        #pragma unroll
        for (int r = 0; r < 4; ++r) {
          float y = acc[nt][r];
          ssum[nt * 4 + r] += y;
          ssq [nt * 4 + r]  = fmaf(y, y, ssq[nt * 4 + r]);
        }
      __syncthreads();
    } else {
      #pragma unroll
      for (int nt = 0; nt < 4; ++nt)
        #pragma unroll
        for (int r = 0; r < 4; ++r) {
          int row = wid * 16 + (lr >> 4) * 4 + r;
          int r2 = row >> 5;
          int w  = row & 31;
          if (w < 25) {
            int d  = nt * 16 + (lr & 15);
            int wp = (w + d) % 25;
            float y = fmaf(acc[nt][r], cmul[nt * 4 + r], cadd[nt * 4 + r]);
            y += s_raw[r2 * 1700 + wp * 68 + d];
            s_aux[d * 50 + r2 * 25 + wp] = fmaxf(y, 0.f);
          }
        }
      __syncthreads();
      const size_t obase = (size_t)n * 409600 + (size_t)(t0 + rp) * 25;
      for (int i = tid; i < 3200; i += 256) {
        int d   = i / 50;
        int rem = i - d * 50;
        int r2  = rem / 25;
        int wp  = rem - r2 * 25;
        out[obase + (size_t)d * 6400 + r2 * 25 + wp] = s_aux[i];
      }
      __syncthreads();
    }
  }

  if constexpr (PASS == 1) {
    #pragma unroll
    for (int nt = 0; nt < 4; ++nt)
      #pragma unroll
      for (int r = 0; r < 4; ++r) {
        int row = wid * 16 + (lr >> 4) * 4 + r;
        int w = row & 31;
        if (w < 25) {
          int q = w * 64 + nt * 16 + (lr & 15);
          atomicAdd(&s_aux[q],        ssum[nt * 4 + r]);
          atomicAdd(&s_aux[1600 + q], ssq [nt * 4 + r]);
        }
      }
    __syncthreads();
    float* rep = ws + 8000 + (blockIdx.x & 63) * 3200;
    for (int i = tid; i < 3200; i += 256)
      atomicAdd(&rep[i], s_aux[i]);
  }
}

extern "C" void kernel_launch(void* const* d_in, const int* in_sizes, int n_in,
                              void* d_out, int out_size, void* d_ws, size_t ws_size,
                              hipStream_t stream) {
  const float* x0    = (const float*)d_in[0];
  const float* W     = (const float*)d_in[1];
  // d_in[2] Linear_bias: cancels in BN, ignored
  const float* mask  = (const float*)d_in[3];
  const float* gamma = (const float*)d_in[4];
  const float* beta  = (const float*)d_in[5];
  // d_in[6], d_in[7] shift indices: computed analytically, ignored
  float* ws  = (float*)d_ws;
  float* out = (float*)d_out;

  if (ws_size >= WS_NEED) {
    hipMemsetAsync(ws + SUMOFF, 0, 3200 * sizeof(float), stream);
    k_gemm  <<<2048, 256, 0, stream>>>(x0, W, mask, ws);
    k_reduce<<<100,  256, 0, stream>>>(ws);
    k_params<<<7,    256, 0, stream>>>(gamma, beta, ws);
    k_epi   <<<1024, 256, 0, stream>>>(x0, ws, out);
  } else {
    k_prep_f    <<<200,  256, 0, stream>>>(mask, ws);
    k_main_f<1> <<<1024, 256, 0, stream>>>(x0, W, ws, out);
    k_finalize_f<<<7,    256, 0, stream>>>(gamma, beta, ws);
    k_main_f<2> <<<1024, 256, 0, stream>>>(x0, W, ws, out);
  }
}